// Round 8
// baseline (546.852 us; speedup 1.0000x reference)
//
#include <hip/hip_runtime.h>
#include <hip/hip_bf16.h>
#include <math.h>

#define B_  4
#define T_  1024
#define D_  1024
#define H_  16
#define HD_ 64
#define DE_ 64
#define NT_ 8
#define NR_ 64
#define NH_ 4

typedef __attribute__((ext_vector_type(8))) short short8;
typedef __attribute__((ext_vector_type(4))) short short4v;
typedef __attribute__((ext_vector_type(4))) float f4;

// fp32 -> bf16 (RNE)
__device__ __forceinline__ short f2bf(float f) {
    unsigned x = __float_as_uint(f);
    unsigned r = (x + 0x7fffu + ((x >> 16) & 1u)) >> 16;
    return (short)r;
}
__device__ __forceinline__ float bf2f(short s) {
    return __uint_as_float(((unsigned)(unsigned short)s) << 16);
}

// async global->LDS, 16 B per lane; LDS dest = wave-uniform base + lane*16
__device__ __forceinline__ void gld_lds16(const short* g, short* l) {
    __builtin_amdgcn_global_load_lds(
        (const __attribute__((address_space(1))) unsigned int*)g,
        (__attribute__((address_space(3))) unsigned int*)l,
        16, 0, 0);
}

// ---------------------------------------------------------------------------
// x (fp32) -> bf16, 8 elems/thread
// ---------------------------------------------------------------------------
__global__ __launch_bounds__(256) void castx_k(
    const float* __restrict__ x, short* __restrict__ xb)
{
    size_t i = ((size_t)blockIdx.x * 256 + threadIdx.x) * 8;
    float4 v0 = *(const float4*)&x[i];
    float4 v1 = *(const float4*)&x[i + 4];
    short8 o;
    o[0] = f2bf(v0.x); o[1] = f2bf(v0.y); o[2] = f2bf(v0.z); o[3] = f2bf(v0.w);
    o[4] = f2bf(v1.x); o[5] = f2bf(v1.y); o[6] = f2bf(v1.z); o[7] = f2bf(v1.w);
    *(short8*)&xb[i] = o;
}

// ---------------------------------------------------------------------------
// All weight transposes in one launch.  WT[(n*rs+ro)][k] = bf16(W[k][n]).
// ---------------------------------------------------------------------------
struct TJ { const float* src; short* dst; int K, N, rs, ro, base; };
struct TJobs { TJ j[7]; };

__global__ __launch_bounds__(256) void tcast_all(TJobs jb)
{
    int bid = blockIdx.x;
    int ji = 0;
#pragma unroll
    for (int i = 1; i < 7; i++) if (bid >= jb.j[i].base) ji = i;
    const float* src = jb.j[ji].src;
    short* dst = jb.j[ji].dst;
    const int K = jb.j[ji].K, N = jb.j[ji].N;
    const int rs = jb.j[ji].rs, ro = jb.j[ji].ro;
    int rel = bid - jb.j[ji].base;
    int tiles_n = N >> 6;
    int k0 = (rel / tiles_n) * 64, n0 = (rel % tiles_n) * 64;

    __shared__ float tile[64][65];
    const int tid = threadIdx.x;
    const int r = tid >> 4, c = (tid & 15) * 4;
#pragma unroll
    for (int rep = 0; rep < 4; rep++) {
        int rr = rep * 16 + r;
        float4 v = *(const float4*)&src[(size_t)(k0 + rr) * N + n0 + c];
        tile[rr][c] = v.x; tile[rr][c + 1] = v.y; tile[rr][c + 2] = v.z; tile[rr][c + 3] = v.w;
    }
    __syncthreads();
#pragma unroll
    for (int rep = 0; rep < 4; rep++) {
        int n = rep * 16 + r;
        short4v p;
        p[0] = f2bf(tile[c + 0][n]);
        p[1] = f2bf(tile[c + 1][n]);
        p[2] = f2bf(tile[c + 2][n]);
        p[3] = f2bf(tile[c + 3][n]);
        *(short4v*)&dst[(size_t)((n0 + n) * rs + ro) * K + k0 + c] = p;
    }
}

// W_type [1024][8] -> BTe rows 64..71 (row n holds W_type[:,n])
__global__ __launch_bounds__(256) void ttype_k(
    const float* __restrict__ Wt, short* __restrict__ BTe)
{
    int idx = blockIdx.x * 256 + threadIdx.x;   // 8192
    int n = idx >> 10, k = idx & 1023;
    BTe[(size_t)(64 + n) * 1024 + k] = f2bf(Wt[k * 8 + n]);
}

// ---------------------------------------------------------------------------
// bf16 MFMA GEMM v3: global_load_lds staging, fragment-major LDS chunks.
// Block tile = (32*AM) x (32*AN), BK=64, 4 waves in 2x2, wave tile 16AM x 16AN.
// LDS: chunk c (1 KB) holds lane l -> (row g*16+(l&15), k kh*32+(l>>4)*8),
// c = g*2+kh for A, 4*AM + g*2+kh for B.  Chunks are both the exact
// global_load_lds lane order AND conflict-free ds_read_b128 fragments.
// A = [A1 (k<Ks) | A2 (k>=Ks)]; B as BT[N,K].
// epi: 0 C f32; 1 +resid -> C f32 + Cb1 bf16; 2 split bf16 at col 1024;
// 3 silu(acc+ent*w1e+bias) -> Cb1 bf16; 5 interleaved combine -> Cb1 bf16.
// ---------------------------------------------------------------------------
template<int AM, int AN>
__global__ __launch_bounds__(256) void gemm3(
    const short* __restrict__ A1, const short* __restrict__ A2, int Ks,
    const short* __restrict__ BT,
    float* __restrict__ C, short* __restrict__ Cb1, short* __restrict__ Cb2,
    int M, int N, int K, int epi,
    const float* __restrict__ resid, const float* __restrict__ ent,
    const float* __restrict__ w1e, const float* __restrict__ bias,
    const float* __restrict__ altw, const float* __restrict__ hitsig)
{
    constexpr int BM = 32 * AM, BN = 32 * AN;
    constexpr int PW = AM + AN;            // chunks per wave
    constexpr int NCHK = 4 * PW;
    __shared__ short L[NCHK * 512];
    const int tid = threadIdx.x, wave = tid >> 6, lane = tid & 63;
    const int lrow = lane & 15, lq = lane >> 4;
    // XCD swizzle
    int bid = blockIdx.x;
    int tiles_m = M / BM;
    int mpx = tiles_m >> 3;
    int xcd = bid & 7, idx = bid >> 3;
    int mt = xcd * mpx + (idx % mpx);
    int nt = idx / mpx;
    const int m0 = mt * BM, n0 = nt * BN;
    const int K2 = K - Ks;
    const int gm = (wave >> 1) * AM, gn = (wave & 1) * AN;

    // per-wave chunk pointers
    const short* cur[PW];
    const short* alt[PW];
    short* lb[PW];
#pragma unroll
    for (int u = 0; u < PW; u++) {
        int c = wave * PW + u;
        lb[u] = &L[c * 512];
        int kk, row;
        if (c < 4 * AM) {               // A chunk
            int g = c >> 1, kh = c & 1;
            kk = kh * 32 + lq * 8;
            row = m0 + g * 16 + lrow;
            cur[u] = A1 + (size_t)row * Ks + kk;
            alt[u] = A2 + (size_t)row * K2 + kk;   // add (k0-Ks) later
        } else {                        // B chunk
            int cb = c - 4 * AM;
            int g = cb >> 1, kh = cb & 1;
            kk = kh * 32 + lq * 8;
            row = n0 + g * 16 + lrow;
            cur[u] = BT + (size_t)row * K + kk;
            alt[u] = cur[u] + Ks;        // so alt at switch == cur + Ks
        }
    }

    f4 acc[AM][AN] = {};

    for (int k0 = 0; k0 < K; k0 += 64) {
        if (k0 == Ks) {                  // uniform, taken once (K-concat only)
#pragma unroll
            for (int u = 0; u < PW; u++) cur[u] = alt[u];
        }
        __syncthreads();                 // prev iter readers done
#pragma unroll
        for (int u = 0; u < PW; u++) {
            gld_lds16(cur[u], lb[u]);
            cur[u] += 64;
        }
        __syncthreads();                 // drains vmcnt (loads landed in LDS)
#pragma unroll
        for (int kh = 0; kh < 2; kh++) {
            short8 af[AM], bfv[AN];
#pragma unroll
            for (int i = 0; i < AM; i++)
                af[i] = *(short8*)&L[(((gm + i) * 2 + kh) * 64 + lane) * 8];
#pragma unroll
            for (int j = 0; j < AN; j++)
                bfv[j] = *(short8*)&L[((4 * AM + (gn + j) * 2 + kh) * 64 + lane) * 8];
#pragma unroll
            for (int i = 0; i < AM; i++)
#pragma unroll
                for (int j = 0; j < AN; j++)
                    acc[i][j] = __builtin_amdgcn_mfma_f32_16x16x32_bf16(
                        af[i], bfv[j], acc[i][j], 0, 0, 0);
        }
    }

#pragma unroll
    for (int i = 0; i < AM; i++) {
#pragma unroll
        for (int r = 0; r < 4; r++) {
            int row = m0 + (gm + i) * 16 + lq * 4 + r;
            float w0 = 0.f, w1 = 0.f, hs = 0.f;
            if (epi == 5) { w0 = altw[row * 2]; w1 = altw[row * 2 + 1]; hs = hitsig[row]; }
#pragma unroll
            for (int j = 0; j < AN; j++) {
                int col = n0 + (gn + j) * 16 + lrow;
                float v = acc[i][j][r];
                if (epi == 0) {
                    C[(size_t)row * N + col] = v;
                } else if (epi == 1) {
                    v += resid[(size_t)row * N + col];
                    C[(size_t)row * N + col] = v;
                    Cb1[(size_t)row * N + col] = f2bf(v);
                } else if (epi == 2) {
                    if (col < 1024) Cb1[(size_t)row * 1024 + col] = f2bf(v);
                    else            Cb2[(size_t)row * 1024 + col - 1024] = f2bf(v);
                } else if (epi == 3) {
                    v += ent[row] * w1e[col] + bias[col];
                    float sv = v * __builtin_amdgcn_rcpf(1.f + __expf(-v));  // silu
                    Cb1[(size_t)row * N + col] = f2bf(sv);
                } else {   // 5: interleaved combine (pairs in adjacent lanes)
                    float other = __shfl_xor(v, 1);
                    if ((lane & 1) == 0) {
                        float cv = (w0 * v + w1 * other) * hs;
                        Cb1[(size_t)row * 1024 + (col >> 1)] = f2bf(cv);
                    }
                }
            }
        }
    }
}

// ---------------------------------------------------------------------------
// vtg[b][h][d][t] = values_bf[b][t][h*64+d]
// ---------------------------------------------------------------------------
__global__ __launch_bounds__(256) void vtrans_k(
    const short* __restrict__ vb, short* __restrict__ vtg)
{
    const int b = blockIdx.z, h = blockIdx.y, t0 = blockIdx.x * 64;
    const int tid = threadIdx.x;
    __shared__ short tile[64 * 72];
    const int row = tid >> 2, c = (tid & 3) * 16;
    const short* p = vb + (size_t)(b * T_ + t0 + row) * D_ + h * 64 + c;
    *(short8*)&tile[row * 72 + c + 0] = *(const short8*)(p + 0);
    *(short8*)&tile[row * 72 + c + 8] = *(const short8*)(p + 8);
    __syncthreads();
    short8 o0, o1;
#pragma unroll
    for (int i = 0; i < 8; i++) o0[i] = tile[(c + i) * 72 + row];
#pragma unroll
    for (int i = 0; i < 8; i++) o1[i] = tile[(c + 8 + i) * 72 + row];
    short* q = vtg + (size_t)((b * H_ + h) * 64 + row) * T_ + t0 + c;
    *(short8*)(q + 0) = o0;
    *(short8*)(q + 8) = o1;
}

// ---------------------------------------------------------------------------
// ax[b,h,t] = dot(nodes_bf[b,t,h,:], arity_w[h,:])
// ---------------------------------------------------------------------------
__global__ __launch_bounds__(256) void ax_k(
    const short* __restrict__ nodes_bf, const float* __restrict__ arity_w,
    float* __restrict__ ax)
{
    int idx = blockIdx.x * 256 + threadIdx.x;
    int t = idx & (T_ - 1);
    int h = (idx >> 10) & (H_ - 1);
    int b = idx >> 14;
    const short* np_ = nodes_bf + (((size_t)b * T_ + t) * H_ + h) * HD_;
    float s = 0.f;
#pragma unroll
    for (int d = 0; d < HD_; d += 8) {
        short8 n8 = *(const short8*)&np_[d];
#pragma unroll
        for (int q = 0; q < 8; q++) s += bf2f(n8[q]) * arity_w[h * HD_ + d + q];
    }
    ax[idx] = s;
}

// ---------------------------------------------------------------------------
// MFMA flash attention v5 (poly sigmoid, no rescale).
// ---------------------------------------------------------------------------
__global__ __launch_bounds__(256) void attn5_k(
    const short* __restrict__ nodes_bf, const short* __restrict__ vtg,
    const float* __restrict__ ax, short* __restrict__ attnp)
{
    const int b = blockIdx.z, h = blockIdx.y, t0 = blockIdx.x * 64;
    const int tid = threadIdx.x;
    const int wave = tid >> 6, lane = tid & 63;
    const int lrow = lane & 15, lq = lane >> 4;
    const int wm = wave * 16;
    const int row = tid >> 2, c = (tid & 3) * 16;

    __shared__ short Nt[64 * 72];
    __shared__ short Ns[64 * 72];
    __shared__ short Vt[64 * 72];
    __shared__ short Pm[64 * 72];
    __shared__ float axs_sh[64];

    {
        const short* p = nodes_bf + (size_t)(b * T_ + t0 + row) * D_ + h * 64 + c;
        *(short8*)&Nt[row * 72 + c + 0] = *(const short8*)(p + 0);
        *(short8*)&Nt[row * 72 + c + 8] = *(const short8*)(p + 8);
    }
    const float at = ax[(size_t)(b * H_ + h) * T_ + t0 + wm + lrow];
    __syncthreads();
    short8 bt0 = *(short8*)&Nt[(wm + lrow) * 72 + lq * 8];
    short8 bt1 = *(short8*)&Nt[(wm + lrow) * 72 + 32 + lq * 8];

    float l_reg = 0.f;
    f4 O[4] = {};

    for (int s0 = 0; s0 < T_; s0 += 64) {
        __syncthreads();
        {
            const short* p = nodes_bf + (size_t)(b * T_ + s0 + row) * D_ + h * 64 + c;
            *(short8*)&Ns[row * 72 + c + 0] = *(const short8*)(p + 0);
            *(short8*)&Ns[row * 72 + c + 8] = *(const short8*)(p + 8);
            const short* q = vtg + (size_t)((b * H_ + h) * 64 + row) * T_ + s0 + c;
            *(short8*)&Vt[row * 72 + c + 0] = *(const short8*)(q + 0);
            *(short8*)&Vt[row * 72 + c + 8] = *(const short8*)(q + 8);
        }
        if (tid < 64) axs_sh[tid] = ax[(size_t)(b * H_ + h) * T_ + s0 + tid];
        __syncthreads();

        float psum = 0.f;
#pragma unroll
        for (int j = 0; j < 4; j++) {
            short8 a0 = *(short8*)&Ns[(j * 16 + lrow) * 72 + lq * 8];
            short8 a1 = *(short8*)&Ns[(j * 16 + lrow) * 72 + 32 + lq * 8];
            f4 s = {0.f, 0.f, 0.f, 0.f};
            s = __builtin_amdgcn_mfma_f32_16x16x32_bf16(a0, bt0, s, 0, 0, 0);
            s = __builtin_amdgcn_mfma_f32_16x16x32_bf16(a1, bt1, s, 0, 0, 0);
            f4 as4 = *(f4*)&axs_sh[j * 16 + lq * 4];
            short4v pw;
#pragma unroll
            for (int r = 0; r < 4; r++) {
                float z = (at + as4[r]) * 0.125f;
                float mod = 0.5f + z * (0.25f - z * z * 0.020833333f);  // sigmoid(z)
                float p = __expf(s[r] * 0.125f * mod);
                psum += p;
                pw[r] = f2bf(p);
            }
            *(short4v*)&Pm[(wm + lrow) * 72 + j * 16 + lq * 4] = pw;
        }
        psum += __shfl_xor(psum, 16);
        psum += __shfl_xor(psum, 32);
        l_reg += psum;
        // Pm rows are wave-private: no block barrier needed before PV.

        short8 pa0 = *(short8*)&Pm[(wm + lrow) * 72 + lq * 8];
        short8 pa1 = *(short8*)&Pm[(wm + lrow) * 72 + 32 + lq * 8];
#pragma unroll
        for (int dj = 0; dj < 4; dj++) {
            short8 v0 = *(short8*)&Vt[(dj * 16 + lrow) * 72 + lq * 8];
            short8 v1 = *(short8*)&Vt[(dj * 16 + lrow) * 72 + 32 + lq * 8];
            O[dj] = __builtin_amdgcn_mfma_f32_16x16x32_bf16(pa0, v0, O[dj], 0, 0, 0);
            O[dj] = __builtin_amdgcn_mfma_f32_16x16x32_bf16(pa1, v1, O[dj], 0, 0, 0);
        }
    }

    float linv[4];
#pragma unroll
    for (int r = 0; r < 4; r++)
        linv[r] = __builtin_amdgcn_rcpf(__shfl(l_reg, lq * 4 + r));
#pragma unroll
    for (int dj = 0; dj < 4; dj++)
#pragma unroll
        for (int r = 0; r < 4; r++)
            attnp[(size_t)(b * T_ + t0 + wm + lq * 4 + r) * D_ + h * 64 + dj * 16 + lrow] =
                f2bf(O[dj][r] * linv[r]);
}

// ---------------------------------------------------------------------------
__global__ __launch_bounds__(64) void pnorm_k(
    const float* __restrict__ patterns, float* __restrict__ pn)
{
    int r = blockIdx.x, lane = threadIdx.x;
    float v = patterns[r * 64 + lane];
    float ss = v * v;
    for (int off = 1; off < 64; off <<= 1) ss += __shfl_xor(ss, off);
    pn[r * 64 + lane] = v / fmaxf(sqrtf(ss), 1e-12f);
}

// ---------------------------------------------------------------------------
// Per-token tail: entropy, event norm, sim (LDS), butterfly top-4, softmaxes.
// ---------------------------------------------------------------------------
__global__ __launch_bounds__(256) void token2_k(
    const float* __restrict__ evlg, const float* __restrict__ pn,
    const float* __restrict__ patterns, const float* __restrict__ W_alt,
    const float* __restrict__ log_temp,
    float* __restrict__ entn, float* __restrict__ altw, float* __restrict__ hitsig)
{
    const int tid = threadIdx.x, wave = tid >> 6, lane = tid & 63;
    __shared__ float pn_sh[64 * 68];
    __shared__ float pat_sh[64 * 68];
    __shared__ float en_sh[4][68];
    {
        int row = tid >> 2, c = (tid & 3) * 16;
#pragma unroll
        for (int u = 0; u < 4; u++) {
            *(float4*)&pn_sh[row * 68 + c + u * 4]  = *(const float4*)&pn[row * 64 + c + u * 4];
            *(float4*)&pat_sh[row * 68 + c + u * 4] = *(const float4*)&patterns[row * 64 + c + u * 4];
        }
    }
    float temp = expf(log_temp[0]);
    temp = fminf(fmaxf(temp, 0.01f), 10.f);
    const float tinv = 1.f / temp;
    __syncthreads();

#pragma unroll
    for (int rep = 0; rep < 2; rep++) {
        const int m = blockIdx.x * 8 + wave * 2 + rep;
        float ev = evlg[(size_t)m * 128 + lane];
        float ss = ev * ev;
        for (int off = 1; off < 64; off <<= 1) ss += __shfl_xor(ss, off);
        float en = ev * __builtin_amdgcn_rcpf(fmaxf(sqrtf(ss), 1e-12f));
        en_sh[wave][lane] = en;
        float entv;
        {
            float lgt = evlg[(size_t)m * 128 + 64 + (lane & 7)];
            float mx = lgt;
            for (int off = 1; off < 8; off <<= 1) mx = fmaxf(mx, __shfl_xor(mx, off));
            float p = __expf(lgt - mx);
            float sum = p;
            for (int off = 1; off < 8; off <<= 1) sum += __shfl_xor(sum, off);
            float pi = p / sum;
            float term = -pi * __logf(pi + 1e-10f);
            float e = term;
            for (int off = 1; off < 8; off <<= 1) e += __shfl_xor(e, off);
            entv = e * 0.4808983f;   // 1/ln(8)
        }
        float sim = 0.f;
#pragma unroll
        for (int u = 0; u < 16; u++) {
            float4 e4 = *(float4*)&en_sh[wave][u * 4];
            float4 p4 = *(float4*)&pn_sh[lane * 68 + u * 4];
            sim += e4.x * p4.x + e4.y * p4.y + e4.z * p4.z + e4.w * p4.w;
        }
        float v = sim;
        float tv[NH_]; int tix[NH_];
#pragma unroll
        for (int kk = 0; kk < NH_; kk++) {
            float mv = v; int mi = lane;
            if (v == -1e30f) mi = 127;
            for (int off = 1; off < 64; off <<= 1) {
                float ov = __shfl_xor(mv, off);
                int   oi = __shfl_xor(mi, off);
                if (ov > mv || (ov == mv && oi < mi)) { mv = ov; mi = oi; }
            }
            tv[kk] = mv; tix[kk] = mi;
            if (lane == mi) v = -1e30f;
        }
        float hmx = tv[0];
        float hw[NH_], hsum = 0.f;
#pragma unroll
        for (int kk = 0; kk < NH_; kk++) { hw[kk] = __expf((tv[kk] - hmx) * tinv); hsum += hw[kk]; }
        float hsr = __builtin_amdgcn_rcpf(hsum);
        float wp = 0.f;
#pragma unroll
        for (int kk = 0; kk < NH_; kk++) wp += hw[kk] * hsr * pat_sh[tix[kk] * 68 + lane];
        float a0 = wp * W_alt[lane * 2 + 0];
        float a1 = wp * W_alt[lane * 2 + 1];
        for (int off = 1; off < 64; off <<= 1) {
            a0 += __shfl_xor(a0, off);
            a1 += __shfl_xor(a1, off);
        }
        a0 *= tinv; a1 *= tinv;
        float amx = fmaxf(a0, a1);
        float e0 = __expf(a0 - amx), e1 = __expf(a1 - amx);
        if (lane == 0) {
            float zr = __builtin_amdgcn_rcpf(e0 + e1);
            altw[m * 2 + 0] = e0 * zr;
            altw[m * 2 + 1] = e1 * zr;
            hitsig[m] = __builtin_amdgcn_rcpf(1.f + __expf(-tv[0]));
            entn[m] = entv;
        }
    }
}

// ---------------------------------------------------------------------------
// g = sigmoid(h1 . Wg2 + bg2); out = x1 + g * actions   (h1, actions bf16)
// ---------------------------------------------------------------------------
__global__ __launch_bounds__(256) void gate_k(
    const short* __restrict__ h1_bf, const float* __restrict__ Wg2,
    const float* __restrict__ bg2, const float* __restrict__ x1,
    const short* __restrict__ actions_bf, float* __restrict__ out)
{
    const int m = blockIdx.x, tid = threadIdx.x;
    float part = 0.f;
    for (int d = tid; d < D_; d += 256)
        part += bf2f(h1_bf[(size_t)m * D_ + d]) * Wg2[d];
    __shared__ float red[256];
    red[tid] = part;
    __syncthreads();
    for (int w = 128; w > 0; w >>= 1) {
        if (tid < w) red[tid] += red[tid + w];
        __syncthreads();
    }
    float g = 1.f / (1.f + expf(-(red[0] + bg2[0])));
    for (int d = tid; d < D_; d += 256) {
        size_t i = (size_t)m * D_ + d;
        out[i] = x1[i] + g * bf2f(actions_bf[i]);
    }
}

// ---------------------------------------------------------------------------
extern "C" void kernel_launch(void* const* d_in, const int* in_sizes, int n_in,
                              void* d_out, int out_size, void* d_ws, size_t ws_size,
                              hipStream_t stream)
{
    const float* x        = (const float*)d_in[0];
    const float* W_node   = (const float*)d_in[1];
    const float* W_value  = (const float*)d_in[2];
    const float* W_out    = (const float*)d_in[3];
    const float* arity_w  = (const float*)d_in[4];
    const float* W_event  = (const float*)d_in[5];
    const float* W_type   = (const float*)d_in[6];
    const float* patterns = (const float*)d_in[7];
    const float* W_act    = (const float*)d_in[8];
    const float* W_alt    = (const float*)d_in[9];
    const float* log_temp = (const float*)d_in[10];
    const float* Wg1      = (const float*)d_in[11];
    const float* bg1      = (const float*)d_in[12];
    const float* Wg2      = (const float*)d_in[13];
    const float* bg2      = (const float*)d_in[14];
    float* out = (float*)d_out;

    const int M = B_ * T_;                          // 4096
    // --- fp32 ---
    float* x1     = (float*)d_ws;                   // 4M floats
    float* evlg   = x1 + 4194304;                   // 512K  [M][128]
    float* axp    = evlg + 524288;                  // 64K
    float* pn     = axp + 65536;
    float* entn   = pn + 4096;
    float* altw   = entn + 4096;
    float* hitsig = altw + 8192;
    // --- bf16 ---
    short* big       = (short*)(hitsig + 4096);
    short* xbf       = big;                         // 4M (x cast; attn out; h1_bf)
    short* nodes_bf  = big + 1 * 4194304;
    short* values_bf = big + 2 * 4194304;
    short* vtg       = big + 3 * 4194304;           // later actions_bf
    short* x1_bf     = big + 4 * 4194304;
    short* wts       = big + 5 * 4194304;
    short* WnvT  = wts;                             // 2M  ([2048][1024])
    short* WoT   = wts + 2 * 1048576;               // 1M
    short* WaT   = wts + 3 * 1048576;               // 2M  interleaved [2048][1024]
    short* Wg1T  = wts + 5 * 1048576;               // 2M  ([1024][2048])
    short* BTe   = wts + 7 * 1048576;               // 128K shorts ([128][1024])
    short* actions_bf = vtg;
    short* h1_bf      = xbf;

    dim3 blk(256);
    dim3 g_bh(T_ / 64, H_, B_);

    castx_k<<<2048, blk, 0, stream>>>(x, xbf);
    pnorm_k<<<NR_, 64, 0, stream>>>(patterns, pn);
    TJobs jb;
    jb.j[0] = {W_node,            WnvT,           1024, 1024, 1, 0,    0};
    jb.j[1] = {W_value,           WnvT + 1048576, 1024, 1024, 1, 0,  256};
    jb.j[2] = {W_out,             WoT,            1024, 1024, 1, 0,  512};
    jb.j[3] = {W_act,             WaT,            1024, 1024, 2, 0,  768};
    jb.j[4] = {W_act + 1048576,   WaT,            1024, 1024, 2, 1, 1024};
    jb.j[5] = {Wg1,               Wg1T,           2048, 1024, 1, 0, 1280};
    jb.j[6] = {W_event,           BTe,            1024,   64, 1, 0, 1792};
    tcast_all<<<1808, blk, 0, stream>>>(jb);
    ttype_k<<<32, blk, 0, stream>>>(W_type, BTe);

    // QKV fused: N=2048, split bf16 outputs (512 blocks, 128x128 tiles)
    gemm3<4, 4><<<512, blk, 0, stream>>>(xbf, xbf, D_, WnvT,
        nullptr, nodes_bf, values_bf, M, 2048, D_, 2,
        nullptr, nullptr, nullptr, nullptr, nullptr, nullptr);
    ax_k<<<256, blk, 0, stream>>>(nodes_bf, arity_w, axp);
    vtrans_k<<<g_bh, blk, 0, stream>>>(values_bf, vtg);
    attn5_k<<<g_bh, blk, 0, stream>>>(nodes_bf, vtg, axp, xbf);   // xbf = attn out
    // x1 = attn@W_out + x (512 blocks, 64x128 tiles)
    gemm3<2, 4><<<512, blk, 0, stream>>>(xbf, xbf, D_, WoT,
        x1, x1_bf, nullptr, M, D_, D_, 1,
        x, nullptr, nullptr, nullptr, nullptr, nullptr);
    // events + type logits: N=128 (64 blocks)
    gemm3<2, 4><<<64, blk, 0, stream>>>(x1_bf, x1_bf, D_, BTe,
        evlg, nullptr, nullptr, M, 128, D_, 0,
        nullptr, nullptr, nullptr, nullptr, nullptr, nullptr);
    token2_k<<<M / 8, blk, 0, stream>>>(evlg, pn, patterns, W_alt, log_temp,
                                        entn, altw, hitsig);
    // actions = combine(x1 @ [Wa0|Wa1]-interleaved) (512 blocks)
    gemm3<4, 4><<<512, blk, 0, stream>>>(x1_bf, x1_bf, D_, WaT,
        nullptr, actions_bf, nullptr, M, 2048, D_, 5,
        nullptr, nullptr, nullptr, nullptr, altw, hitsig);
    // h1 = silu([x1|actions] @ Wg1 + ent*w_row2048 + bg1)  (K=2048, 512 blocks)
    gemm3<2, 4><<<512, blk, 0, stream>>>(x1_bf, actions_bf, D_, Wg1T,
        nullptr, h1_bf, nullptr, M, D_, 2048, 3,
        nullptr, entn, Wg1 + (size_t)2048 * D_, bg1, nullptr, nullptr);
    gate_k<<<M, blk, 0, stream>>>(h1_bf, Wg2, bg2, x1, actions_bf, out);
}

// Round 9
// 346.469 us; speedup vs baseline: 1.5784x; 1.5784x over previous
//
#include <hip/hip_runtime.h>
#include <hip/hip_bf16.h>
#include <math.h>

#define B_  4
#define T_  1024
#define D_  1024
#define H_  16
#define HD_ 64
#define DE_ 64
#define NT_ 8
#define NR_ 64
#define NH_ 4

typedef __attribute__((ext_vector_type(8))) short short8;
typedef __attribute__((ext_vector_type(4))) short short4v;
typedef __attribute__((ext_vector_type(4))) float f4;

// fp32 -> bf16 (RNE)
__device__ __forceinline__ short f2bf(float f) {
    unsigned x = __float_as_uint(f);
    unsigned r = (x + 0x7fffu + ((x >> 16) & 1u)) >> 16;
    return (short)r;
}
__device__ __forceinline__ float bf2f(short s) {
    return __uint_as_float(((unsigned)(unsigned short)s) << 16);
}

// ---------------------------------------------------------------------------
// x (fp32) -> bf16, 8 elems/thread
// ---------------------------------------------------------------------------
__global__ __launch_bounds__(256) void castx_k(
    const float* __restrict__ x, short* __restrict__ xb)
{
    size_t i = ((size_t)blockIdx.x * 256 + threadIdx.x) * 8;
    float4 v0 = *(const float4*)&x[i];
    float4 v1 = *(const float4*)&x[i + 4];
    short8 o;
    o[0] = f2bf(v0.x); o[1] = f2bf(v0.y); o[2] = f2bf(v0.z); o[3] = f2bf(v0.w);
    o[4] = f2bf(v1.x); o[5] = f2bf(v1.y); o[6] = f2bf(v1.z); o[7] = f2bf(v1.w);
    *(short8*)&xb[i] = o;
}

// ---------------------------------------------------------------------------
// All weight transposes in one launch.  WT[(n*rs+ro)][k] = bf16(W[k][n]).
// ---------------------------------------------------------------------------
struct TJ { const float* src; short* dst; int K, N, rs, ro, base; };
struct TJobs { TJ j[7]; };

__global__ __launch_bounds__(256) void tcast_all(TJobs jb)
{
    int bid = blockIdx.x;
    int ji = 0;
#pragma unroll
    for (int i = 1; i < 7; i++) if (bid >= jb.j[i].base) ji = i;
    const float* src = jb.j[ji].src;
    short* dst = jb.j[ji].dst;
    const int K = jb.j[ji].K, N = jb.j[ji].N;
    const int rs = jb.j[ji].rs, ro = jb.j[ji].ro;
    int rel = bid - jb.j[ji].base;
    int tiles_n = N >> 6;
    int k0 = (rel / tiles_n) * 64, n0 = (rel % tiles_n) * 64;

    __shared__ float tile[64][65];
    const int tid = threadIdx.x;
    const int r = tid >> 4, c = (tid & 15) * 4;
#pragma unroll
    for (int rep = 0; rep < 4; rep++) {
        int rr = rep * 16 + r;
        float4 v = *(const float4*)&src[(size_t)(k0 + rr) * N + n0 + c];
        tile[rr][c] = v.x; tile[rr][c + 1] = v.y; tile[rr][c + 2] = v.z; tile[rr][c + 3] = v.w;
    }
    __syncthreads();
#pragma unroll
    for (int rep = 0; rep < 4; rep++) {
        int n = rep * 16 + r;
        short4v p;
        p[0] = f2bf(tile[c + 0][n]);
        p[1] = f2bf(tile[c + 1][n]);
        p[2] = f2bf(tile[c + 2][n]);
        p[3] = f2bf(tile[c + 3][n]);
        *(short4v*)&dst[(size_t)((n0 + n) * rs + ro) * K + k0 + c] = p;
    }
}

// W_type [1024][8] -> BTe rows 64..71 (row n holds W_type[:,n])
__global__ __launch_bounds__(256) void ttype_k(
    const float* __restrict__ Wt, short* __restrict__ BTe)
{
    int idx = blockIdx.x * 256 + threadIdx.x;   // 8192
    int n = idx >> 10, k = idx & 1023;
    BTe[(size_t)(64 + n) * 1024 + k] = f2bf(Wt[k * 8 + n]);
}

// ---------------------------------------------------------------------------
// bf16 MFMA GEMM v4: R6 tile shape (BM x 128, BK=64, ds_write staging) plus
// an in-kernel software pipeline: next k-tile is global-loaded into VGPRs
// while the current tile's MFMAs run, so global latency hides behind compute
// even at 2 blocks/CU.  BM = AM*32 (AM=4 -> 128, AM=2 -> 64); 4 waves 2x2,
// wave tile (AM*16) x 64.  A = [A1 (k<Ks) | A2 (k>=Ks)]; B as BT[N,K].
// epi: 0 C f32; 1 +resid -> C f32 + Cb1 bf16; 2 split bf16 at col 1024;
// 3 silu(acc+ent*w1e+bias) -> Cb1 bf16; 5 interleaved combine -> Cb1 bf16.
// ---------------------------------------------------------------------------
template<int AM>
__global__ __launch_bounds__(256) void gemm4(
    const short* __restrict__ A1, const short* __restrict__ A2, int Ks,
    const short* __restrict__ BT,
    float* __restrict__ C, short* __restrict__ Cb1, short* __restrict__ Cb2,
    int M, int N, int K, int epi,
    const float* __restrict__ resid, const float* __restrict__ ent,
    const float* __restrict__ w1e, const float* __restrict__ bias,
    const float* __restrict__ altw, const float* __restrict__ hitsig)
{
    constexpr int BM = AM * 32;
    constexpr int AR = (AM == 4) ? 2 : 4;      // threads per A row
    constexpr int ANV = 64 / AR / 8;           // short8 per thread for A
    __shared__ short As[BM * 72];
    __shared__ short Bs[128 * 72];
    const int tid = threadIdx.x, wave = tid >> 6, lane = tid & 63;
    const int lrow = lane & 15, lq = lane >> 4;
    // XCD swizzle: consecutive bids -> distinct XCDs, M-slab per XCD
    int bid = blockIdx.x;
    int tiles_m = M / BM;
    int mpx = tiles_m >> 3;
    int xcd = bid & 7, idx = bid >> 3;
    int mt = xcd * mpx + (idx % mpx);
    int nt = idx / mpx;
    const int m0 = mt * BM, n0 = nt * 128;
    const int wm = (wave >> 1) * (AM * 16), wn = (wave & 1) * 64;
    const int K2 = K - Ks;
    const int arow = tid / AR, ash = (tid % AR) * (64 / AR);
    const int brow = tid >> 1, bsh = (tid & 1) * 32;

    short8 va[ANV], vb[4];
    auto loadA = [&](int k0) {
        int ka = k0 + ash;
        const short* ap = (ka < Ks)
            ? A1 + (size_t)(m0 + arow) * Ks + ka
            : A2 + (size_t)(m0 + arow) * K2 + (ka - Ks);
#pragma unroll
        for (int u = 0; u < ANV; u++) va[u] = *(const short8*)(ap + u * 8);
    };
    auto loadB = [&](int k0) {
        const short* bp = BT + (size_t)(n0 + brow) * K + k0 + bsh;
#pragma unroll
        for (int u = 0; u < 4; u++) vb[u] = *(const short8*)(bp + u * 8);
    };

    loadA(0); loadB(0);
    f4 acc[AM][4] = {};

    for (int k0 = 0; k0 < K; k0 += 64) {
        __syncthreads();                 // prev-iter LDS readers done
#pragma unroll
        for (int u = 0; u < ANV; u++)
            *(short8*)&As[arow * 72 + ash + u * 8] = va[u];
#pragma unroll
        for (int u = 0; u < 4; u++)
            *(short8*)&Bs[brow * 72 + bsh + u * 8] = vb[u];
        __syncthreads();
        if (k0 + 64 < K) { loadA(k0 + 64); loadB(k0 + 64); }  // in flight over MFMAs
#pragma unroll
        for (int kh = 0; kh < 2; kh++) {
            short8 af[AM], bfv[4];
#pragma unroll
            for (int i = 0; i < AM; i++)
                af[i] = *(short8*)&As[(wm + i * 16 + lrow) * 72 + kh * 32 + lq * 8];
#pragma unroll
            for (int j = 0; j < 4; j++)
                bfv[j] = *(short8*)&Bs[(wn + j * 16 + lrow) * 72 + kh * 32 + lq * 8];
#pragma unroll
            for (int i = 0; i < AM; i++)
#pragma unroll
                for (int j = 0; j < 4; j++)
                    acc[i][j] = __builtin_amdgcn_mfma_f32_16x16x32_bf16(
                        af[i], bfv[j], acc[i][j], 0, 0, 0);
        }
    }

#pragma unroll
    for (int i = 0; i < AM; i++) {
#pragma unroll
        for (int r = 0; r < 4; r++) {
            int row = m0 + wm + i * 16 + lq * 4 + r;
            float w0 = 0.f, w1 = 0.f, hs = 0.f;
            if (epi == 5) { w0 = altw[row * 2]; w1 = altw[row * 2 + 1]; hs = hitsig[row]; }
#pragma unroll
            for (int j = 0; j < 4; j++) {
                int col = n0 + wn + j * 16 + lrow;
                float v = acc[i][j][r];
                if (epi == 0) {
                    C[(size_t)row * N + col] = v;
                } else if (epi == 1) {
                    v += resid[(size_t)row * N + col];
                    C[(size_t)row * N + col] = v;
                    Cb1[(size_t)row * N + col] = f2bf(v);
                } else if (epi == 2) {
                    if (col < 1024) Cb1[(size_t)row * 1024 + col] = f2bf(v);
                    else            Cb2[(size_t)row * 1024 + col - 1024] = f2bf(v);
                } else if (epi == 3) {
                    v += ent[row] * w1e[col] + bias[col];
                    float sv = v * __builtin_amdgcn_rcpf(1.f + __expf(-v));  // silu
                    Cb1[(size_t)row * N + col] = f2bf(sv);
                } else {   // 5: interleaved combine (alt pair in adjacent lanes)
                    float other = __shfl_xor(v, 1);
                    if ((lane & 1) == 0) {
                        float cv = (w0 * v + w1 * other) * hs;
                        Cb1[(size_t)row * 1024 + (col >> 1)] = f2bf(cv);
                    }
                }
            }
        }
    }
}

// ---------------------------------------------------------------------------
// vtg[b][h][d][t] = values_bf[b][t][h*64+d]
// ---------------------------------------------------------------------------
__global__ __launch_bounds__(256) void vtrans_k(
    const short* __restrict__ vb, short* __restrict__ vtg)
{
    const int b = blockIdx.z, h = blockIdx.y, t0 = blockIdx.x * 64;
    const int tid = threadIdx.x;
    __shared__ short tile[64 * 72];
    const int row = tid >> 2, c = (tid & 3) * 16;
    const short* p = vb + (size_t)(b * T_ + t0 + row) * D_ + h * 64 + c;
    *(short8*)&tile[row * 72 + c + 0] = *(const short8*)(p + 0);
    *(short8*)&tile[row * 72 + c + 8] = *(const short8*)(p + 8);
    __syncthreads();
    short8 o0, o1;
#pragma unroll
    for (int i = 0; i < 8; i++) o0[i] = tile[(c + i) * 72 + row];
#pragma unroll
    for (int i = 0; i < 8; i++) o1[i] = tile[(c + 8 + i) * 72 + row];
    short* q = vtg + (size_t)((b * H_ + h) * 64 + row) * T_ + t0 + c;
    *(short8*)(q + 0) = o0;
    *(short8*)(q + 8) = o1;
}

// ---------------------------------------------------------------------------
// ax[b,h,t] = dot(nodes_bf[b,t,h,:], arity_w[h,:])
// ---------------------------------------------------------------------------
__global__ __launch_bounds__(256) void ax_k(
    const short* __restrict__ nodes_bf, const float* __restrict__ arity_w,
    float* __restrict__ ax)
{
    int idx = blockIdx.x * 256 + threadIdx.x;
    int t = idx & (T_ - 1);
    int h = (idx >> 10) & (H_ - 1);
    int b = idx >> 14;
    const short* np_ = nodes_bf + (((size_t)b * T_ + t) * H_ + h) * HD_;
    float s = 0.f;
#pragma unroll
    for (int d = 0; d < HD_; d += 8) {
        short8 n8 = *(const short8*)&np_[d];
#pragma unroll
        for (int q = 0; q < 8; q++) s += bf2f(n8[q]) * arity_w[h * HD_ + d + q];
    }
    ax[idx] = s;
}

// ---------------------------------------------------------------------------
// MFMA flash attention v5 (poly sigmoid, no rescale).
// ---------------------------------------------------------------------------
__global__ __launch_bounds__(256) void attn5_k(
    const short* __restrict__ nodes_bf, const short* __restrict__ vtg,
    const float* __restrict__ ax, short* __restrict__ attnp)
{
    const int b = blockIdx.z, h = blockIdx.y, t0 = blockIdx.x * 64;
    const int tid = threadIdx.x;
    const int wave = tid >> 6, lane = tid & 63;
    const int lrow = lane & 15, lq = lane >> 4;
    const int wm = wave * 16;
    const int row = tid >> 2, c = (tid & 3) * 16;

    __shared__ short Nt[64 * 72];
    __shared__ short Ns[64 * 72];
    __shared__ short Vt[64 * 72];
    __shared__ short Pm[64 * 72];
    __shared__ float axs_sh[64];

    {
        const short* p = nodes_bf + (size_t)(b * T_ + t0 + row) * D_ + h * 64 + c;
        *(short8*)&Nt[row * 72 + c + 0] = *(const short8*)(p + 0);
        *(short8*)&Nt[row * 72 + c + 8] = *(const short8*)(p + 8);
    }
    const float at = ax[(size_t)(b * H_ + h) * T_ + t0 + wm + lrow];
    __syncthreads();
    short8 bt0 = *(short8*)&Nt[(wm + lrow) * 72 + lq * 8];
    short8 bt1 = *(short8*)&Nt[(wm + lrow) * 72 + 32 + lq * 8];

    float l_reg = 0.f;
    f4 O[4] = {};

    for (int s0 = 0; s0 < T_; s0 += 64) {
        __syncthreads();
        {
            const short* p = nodes_bf + (size_t)(b * T_ + s0 + row) * D_ + h * 64 + c;
            *(short8*)&Ns[row * 72 + c + 0] = *(const short8*)(p + 0);
            *(short8*)&Ns[row * 72 + c + 8] = *(const short8*)(p + 8);
            const short* q = vtg + (size_t)((b * H_ + h) * 64 + row) * T_ + s0 + c;
            *(short8*)&Vt[row * 72 + c + 0] = *(const short8*)(q + 0);
            *(short8*)&Vt[row * 72 + c + 8] = *(const short8*)(q + 8);
        }
        if (tid < 64) axs_sh[tid] = ax[(size_t)(b * H_ + h) * T_ + s0 + tid];
        __syncthreads();

        float psum = 0.f;
#pragma unroll
        for (int j = 0; j < 4; j++) {
            short8 a0 = *(short8*)&Ns[(j * 16 + lrow) * 72 + lq * 8];
            short8 a1 = *(short8*)&Ns[(j * 16 + lrow) * 72 + 32 + lq * 8];
            f4 s = {0.f, 0.f, 0.f, 0.f};
            s = __builtin_amdgcn_mfma_f32_16x16x32_bf16(a0, bt0, s, 0, 0, 0);
            s = __builtin_amdgcn_mfma_f32_16x16x32_bf16(a1, bt1, s, 0, 0, 0);
            f4 as4 = *(f4*)&axs_sh[j * 16 + lq * 4];
            short4v pw;
#pragma unroll
            for (int r = 0; r < 4; r++) {
                float z = (at + as4[r]) * 0.125f;
                float mod = 0.5f + z * (0.25f - z * z * 0.020833333f);  // sigmoid(z)
                float p = __expf(s[r] * 0.125f * mod);
                psum += p;
                pw[r] = f2bf(p);
            }
            *(short4v*)&Pm[(wm + lrow) * 72 + j * 16 + lq * 4] = pw;
        }
        psum += __shfl_xor(psum, 16);
        psum += __shfl_xor(psum, 32);
        l_reg += psum;
        // Pm rows are wave-private: no block barrier needed before PV.

        short8 pa0 = *(short8*)&Pm[(wm + lrow) * 72 + lq * 8];
        short8 pa1 = *(short8*)&Pm[(wm + lrow) * 72 + 32 + lq * 8];
#pragma unroll
        for (int dj = 0; dj < 4; dj++) {
            short8 v0 = *(short8*)&Vt[(dj * 16 + lrow) * 72 + lq * 8];
            short8 v1 = *(short8*)&Vt[(dj * 16 + lrow) * 72 + 32 + lq * 8];
            O[dj] = __builtin_amdgcn_mfma_f32_16x16x32_bf16(pa0, v0, O[dj], 0, 0, 0);
            O[dj] = __builtin_amdgcn_mfma_f32_16x16x32_bf16(pa1, v1, O[dj], 0, 0, 0);
        }
    }

    float linv[4];
#pragma unroll
    for (int r = 0; r < 4; r++)
        linv[r] = __builtin_amdgcn_rcpf(__shfl(l_reg, lq * 4 + r));
#pragma unroll
    for (int dj = 0; dj < 4; dj++)
#pragma unroll
        for (int r = 0; r < 4; r++)
            attnp[(size_t)(b * T_ + t0 + wm + lq * 4 + r) * D_ + h * 64 + dj * 16 + lrow] =
                f2bf(O[dj][r] * linv[r]);
}

// ---------------------------------------------------------------------------
__global__ __launch_bounds__(64) void pnorm_k(
    const float* __restrict__ patterns, float* __restrict__ pn)
{
    int r = blockIdx.x, lane = threadIdx.x;
    float v = patterns[r * 64 + lane];
    float ss = v * v;
    for (int off = 1; off < 64; off <<= 1) ss += __shfl_xor(ss, off);
    pn[r * 64 + lane] = v / fmaxf(sqrtf(ss), 1e-12f);
}

// ---------------------------------------------------------------------------
// Per-token tail: entropy, event norm, sim (LDS), butterfly top-4, softmaxes.
// ---------------------------------------------------------------------------
__global__ __launch_bounds__(256) void token2_k(
    const float* __restrict__ evlg, const float* __restrict__ pn,
    const float* __restrict__ patterns, const float* __restrict__ W_alt,
    const float* __restrict__ log_temp,
    float* __restrict__ entn, float* __restrict__ altw, float* __restrict__ hitsig)
{
    const int tid = threadIdx.x, wave = tid >> 6, lane = tid & 63;
    __shared__ float pn_sh[64 * 68];
    __shared__ float pat_sh[64 * 68];
    __shared__ float en_sh[4][68];
    {
        int row = tid >> 2, c = (tid & 3) * 16;
#pragma unroll
        for (int u = 0; u < 4; u++) {
            *(float4*)&pn_sh[row * 68 + c + u * 4]  = *(const float4*)&pn[row * 64 + c + u * 4];
            *(float4*)&pat_sh[row * 68 + c + u * 4] = *(const float4*)&patterns[row * 64 + c + u * 4];
        }
    }
    float temp = expf(log_temp[0]);
    temp = fminf(fmaxf(temp, 0.01f), 10.f);
    const float tinv = 1.f / temp;
    __syncthreads();

#pragma unroll
    for (int rep = 0; rep < 2; rep++) {
        const int m = blockIdx.x * 8 + wave * 2 + rep;
        float ev = evlg[(size_t)m * 128 + lane];
        float ss = ev * ev;
        for (int off = 1; off < 64; off <<= 1) ss += __shfl_xor(ss, off);
        float en = ev * __builtin_amdgcn_rcpf(fmaxf(sqrtf(ss), 1e-12f));
        en_sh[wave][lane] = en;
        float entv;
        {
            float lgt = evlg[(size_t)m * 128 + 64 + (lane & 7)];
            float mx = lgt;
            for (int off = 1; off < 8; off <<= 1) mx = fmaxf(mx, __shfl_xor(mx, off));
            float p = __expf(lgt - mx);
            float sum = p;
            for (int off = 1; off < 8; off <<= 1) sum += __shfl_xor(sum, off);
            float pi = p / sum;
            float term = -pi * __logf(pi + 1e-10f);
            float e = term;
            for (int off = 1; off < 8; off <<= 1) e += __shfl_xor(e, off);
            entv = e * 0.4808983f;   // 1/ln(8)
        }
        float sim = 0.f;
#pragma unroll
        for (int u = 0; u < 16; u++) {
            float4 e4 = *(float4*)&en_sh[wave][u * 4];
            float4 p4 = *(float4*)&pn_sh[lane * 68 + u * 4];
            sim += e4.x * p4.x + e4.y * p4.y + e4.z * p4.z + e4.w * p4.w;
        }
        float v = sim;
        float tv[NH_]; int tix[NH_];
#pragma unroll
        for (int kk = 0; kk < NH_; kk++) {
            float mv = v; int mi = lane;
            if (v == -1e30f) mi = 127;
            for (int off = 1; off < 64; off <<= 1) {
                float ov = __shfl_xor(mv, off);
                int   oi = __shfl_xor(mi, off);
                if (ov > mv || (ov == mv && oi < mi)) { mv = ov; mi = oi; }
            }
            tv[kk] = mv; tix[kk] = mi;
            if (lane == mi) v = -1e30f;
        }
        float hmx = tv[0];
        float hw[NH_], hsum = 0.f;
#pragma unroll
        for (int kk = 0; kk < NH_; kk++) { hw[kk] = __expf((tv[kk] - hmx) * tinv); hsum += hw[kk]; }
        float hsr = __builtin_amdgcn_rcpf(hsum);
        float wp = 0.f;
#pragma unroll
        for (int kk = 0; kk < NH_; kk++) wp += hw[kk] * hsr * pat_sh[tix[kk] * 68 + lane];
        float a0 = wp * W_alt[lane * 2 + 0];
        float a1 = wp * W_alt[lane * 2 + 1];
        for (int off = 1; off < 64; off <<= 1) {
            a0 += __shfl_xor(a0, off);
            a1 += __shfl_xor(a1, off);
        }
        a0 *= tinv; a1 *= tinv;
        float amx = fmaxf(a0, a1);
        float e0 = __expf(a0 - amx), e1 = __expf(a1 - amx);
        if (lane == 0) {
            float zr = __builtin_amdgcn_rcpf(e0 + e1);
            altw[m * 2 + 0] = e0 * zr;
            altw[m * 2 + 1] = e1 * zr;
            hitsig[m] = __builtin_amdgcn_rcpf(1.f + __expf(-tv[0]));
            entn[m] = entv;
        }
    }
}

// ---------------------------------------------------------------------------
// g = sigmoid(h1 . Wg2 + bg2); out = x1 + g * actions   (h1, actions bf16)
// ---------------------------------------------------------------------------
__global__ __launch_bounds__(256) void gate_k(
    const short* __restrict__ h1_bf, const float* __restrict__ Wg2,
    const float* __restrict__ bg2, const float* __restrict__ x1,
    const short* __restrict__ actions_bf, float* __restrict__ out)
{
    const int m = blockIdx.x, tid = threadIdx.x;
    float part = 0.f;
    for (int d = tid; d < D_; d += 256)
        part += bf2f(h1_bf[(size_t)m * D_ + d]) * Wg2[d];
    __shared__ float red[256];
    red[tid] = part;
    __syncthreads();
    for (int w = 128; w > 0; w >>= 1) {
        if (tid < w) red[tid] += red[tid + w];
        __syncthreads();
    }
    float g = 1.f / (1.f + expf(-(red[0] + bg2[0])));
    for (int d = tid; d < D_; d += 256) {
        size_t i = (size_t)m * D_ + d;
        out[i] = x1[i] + g * bf2f(actions_bf[i]);
    }
}

// ---------------------------------------------------------------------------
extern "C" void kernel_launch(void* const* d_in, const int* in_sizes, int n_in,
                              void* d_out, int out_size, void* d_ws, size_t ws_size,
                              hipStream_t stream)
{
    const float* x        = (const float*)d_in[0];
    const float* W_node   = (const float*)d_in[1];
    const float* W_value  = (const float*)d_in[2];
    const float* W_out    = (const float*)d_in[3];
    const float* arity_w  = (const float*)d_in[4];
    const float* W_event  = (const float*)d_in[5];
    const float* W_type   = (const float*)d_in[6];
    const float* patterns = (const float*)d_in[7];
    const float* W_act    = (const float*)d_in[8];
    const float* W_alt    = (const float*)d_in[9];
    const float* log_temp = (const float*)d_in[10];
    const float* Wg1      = (const float*)d_in[11];
    const float* bg1      = (const float*)d_in[12];
    const float* Wg2      = (const float*)d_in[13];
    const float* bg2      = (const float*)d_in[14];
    float* out = (float*)d_out;

    const int M = B_ * T_;                          // 4096
    // --- fp32 ---
    float* x1     = (float*)d_ws;                   // 4M floats
    float* evlg   = x1 + 4194304;                   // 512K  [M][128]
    float* axp    = evlg + 524288;                  // 64K
    float* pn     = axp + 65536;
    float* entn   = pn + 4096;
    float* altw   = entn + 4096;
    float* hitsig = altw + 8192;
    // --- bf16 ---
    short* big       = (short*)(hitsig + 4096);
    short* xbf       = big;                         // 4M (x cast; attn out; h1_bf)
    short* nodes_bf  = big + 1 * 4194304;
    short* values_bf = big + 2 * 4194304;
    short* vtg       = big + 3 * 4194304;           // later actions_bf
    short* x1_bf     = big + 4 * 4194304;
    short* wts       = big + 5 * 4194304;
    short* WnvT  = wts;                             // 2M  ([2048][1024])
    short* WoT   = wts + 2 * 1048576;               // 1M
    short* WaT   = wts + 3 * 1048576;               // 2M  interleaved [2048][1024]
    short* Wg1T  = wts + 5 * 1048576;               // 2M  ([1024][2048])
    short* BTe   = wts + 7 * 1048576;               // 128K shorts ([128][1024])
    short* actions_bf = vtg;
    short* h1_bf      = xbf;

    dim3 blk(256);
    dim3 g_bh(T_ / 64, H_, B_);

    castx_k<<<2048, blk, 0, stream>>>(x, xbf);
    pnorm_k<<<NR_, 64, 0, stream>>>(patterns, pn);
    TJobs jb;
    jb.j[0] = {W_node,            WnvT,           1024, 1024, 1, 0,    0};
    jb.j[1] = {W_value,           WnvT + 1048576, 1024, 1024, 1, 0,  256};
    jb.j[2] = {W_out,             WoT,            1024, 1024, 1, 0,  512};
    jb.j[3] = {W_act,             WaT,            1024, 1024, 2, 0,  768};
    jb.j[4] = {W_act + 1048576,   WaT,            1024, 1024, 2, 1, 1024};
    jb.j[5] = {Wg1,               Wg1T,           2048, 1024, 1, 0, 1280};
    jb.j[6] = {W_event,           BTe,            1024,   64, 1, 0, 1792};
    tcast_all<<<1808, blk, 0, stream>>>(jb);
    ttype_k<<<32, blk, 0, stream>>>(W_type, BTe);

    // QKV fused: N=2048, split bf16 outputs (512 blocks, 128x128 tiles)
    gemm4<4><<<512, blk, 0, stream>>>(xbf, xbf, D_, WnvT,
        nullptr, nodes_bf, values_bf, M, 2048, D_, 2,
        nullptr, nullptr, nullptr, nullptr, nullptr, nullptr);
    ax_k<<<256, blk, 0, stream>>>(nodes_bf, arity_w, axp);
    vtrans_k<<<g_bh, blk, 0, stream>>>(values_bf, vtg);
    attn5_k<<<g_bh, blk, 0, stream>>>(nodes_bf, vtg, axp, xbf);   // xbf = attn out
    // x1 = attn@W_out + x (512 blocks, 64x128 tiles)
    gemm4<2><<<512, blk, 0, stream>>>(xbf, xbf, D_, WoT,
        x1, x1_bf, nullptr, M, D_, D_, 1,
        x, nullptr, nullptr, nullptr, nullptr, nullptr);
    // events + type logits: N=128 (64 blocks, 64x128 tiles)
    gemm4<2><<<64, blk, 0, stream>>>(x1_bf, x1_bf, D_, BTe,
        evlg, nullptr, nullptr, M, 128, D_, 0,
        nullptr, nullptr, nullptr, nullptr, nullptr, nullptr);
    token2_k<<<M / 8, blk, 0, stream>>>(evlg, pn, patterns, W_alt, log_temp,
                                        entn, altw, hitsig);
    // actions = combine(x1 @ [Wa0|Wa1]-interleaved) (512 blocks, 128x128)
    gemm4<4><<<512, blk, 0, stream>>>(x1_bf, x1_bf, D_, WaT,
        nullptr, actions_bf, nullptr, M, 2048, D_, 5,
        nullptr, nullptr, nullptr, nullptr, altw, hitsig);
    // h1 = silu([x1|actions] @ Wg1 + ent*w_row2048 + bg1)  (K=2048, 512 blocks)
    gemm4<2><<<512, blk, 0, stream>>>(x1_bf, actions_bf, D_, Wg1T,
        nullptr, h1_bf, nullptr, M, D_, 2048, 3,
        nullptr, entn, Wg1 + (size_t)2048 * D_, bg1, nullptr, nullptr);
    gate_k<<<M, blk, 0, stream>>>(h1_bf, Wg2, bg2, x1, actions_bf, out);
}